// Round 7
// baseline (265.138 us; speedup 1.0000x reference)
//
#include <hip/hip_runtime.h>

#define N_NODES 10000
#define NE      80000
#define H       32
#define VD0     2048
#define VD1     256

// prep kernel block-range dispatch
#define NODE_BLOCKS  40                    // (N_NODES+255)/256
#define NC_BLOCKS    2500                  // wave per node (4 waves/block)
#define HIST_BLOCKS  313                   // (NE+255)/256
#define PREP_BLOCKS  (NODE_BLOCKS + 2 * NC_BLOCKS + HIST_BLOCKS)

// fused edge kernel block-range dispatch
// graph0: 4 K-phases (512-elem chunks, uint4/lane — R5's best point); within
// a phase, wave per dst. 8-edge unroll for memory-level parallelism.
#define EDGE0_PHASES  4
#define EDGE0_GBLK    2500                 // dst-groups per phase (4 dsts/block)
#define EDGE0_BLOCKS  (EDGE0_PHASES * EDGE0_GBLK)
#define EDGE1_BLOCKS  2500                 // graph1: 4 dsts per block, wave per dst
#define EDGE_BLOCKS   (EDGE0_BLOCKS + EDGE1_BLOCKS)

// ---------------------------------------------------------------------------
// bf16 helpers
// ---------------------------------------------------------------------------
__device__ inline unsigned short f2bf_rne(float f) {
    unsigned int u = __float_as_uint(f);
    u += 0x7fffu + ((u >> 16) & 1u);
    return (unsigned short)(u >> 16);
}
__device__ inline float bflo(unsigned int u) { return __uint_as_float(u << 16); }
__device__ inline float bfhi(unsigned int u) { return __uint_as_float(u & 0xffff0000u); }

__device__ inline float dot8_bf16(uint4 a, uint4 b) {
    float s;
    s  = bflo(a.x) * bflo(b.x) + bfhi(a.x) * bfhi(b.x);
    s += bflo(a.y) * bflo(b.y) + bfhi(a.y) * bfhi(b.y);
    s += bflo(a.z) * bflo(b.z) + bfhi(a.z) * bfhi(b.z);
    s += bflo(a.w) * bflo(b.w) + bfhi(a.w) * bfhi(b.w);
    return s;
}
__device__ inline float dot4_bf16(uint2 a, uint2 b) {
    return bflo(a.x) * bflo(b.x) + bfhi(a.x) * bfhi(b.x)
         + bflo(a.y) * bflo(b.y) + bfhi(a.y) * bfhi(b.y);
}

// ---------------------------------------------------------------------------
// normconv body: vn[node] = bf16( vis[node] * rsqrt(||vis[node]||^2 + 1e-8) )
// ---------------------------------------------------------------------------
template <int VD>
__device__ inline void normconv_node(const float* __restrict__ vis,
                                     unsigned short* __restrict__ vn,
                                     int node, int lane)
{
    const float4* v = (const float4*)(vis + (size_t)node * VD);
    float4 f[VD / 256];
    float acc = 0.f;
    #pragma unroll
    for (int it = 0; it < VD / 256; it++) {
        f[it] = v[it * 64 + lane];
        acc += f[it].x * f[it].x + f[it].y * f[it].y + f[it].z * f[it].z + f[it].w * f[it].w;
    }
    #pragma unroll
    for (int o = 32; o; o >>= 1) acc += __shfl_xor(acc, o);
    const float inv = rsqrtf(acc + 1e-8f);
    ushort4* o4 = (ushort4*)(vn + (size_t)node * VD);
    #pragma unroll
    for (int it = 0; it < VD / 256; it++) {
        ushort4 r;
        r.x = f2bf_rne(f[it].x * inv);
        r.y = f2bf_rne(f[it].y * inv);
        r.z = f2bf_rne(f[it].z * inv);
        r.w = f2bf_rne(f[it].w * inv);
        o4[it * 64 + lane] = r;
    }
}

// ---------------------------------------------------------------------------
// PREP mega-kernel (block-range dispatch, all paths independent):
//   [0, 40)          node MLP + head folding -> out, p0w, p1w
//   [40, 2540)       normconv graph0 (VD0)
//   [2540, 5040)     normconv graph1 (VD1)
//   [5040, 5353)     dst-degree histograms for both graphs (deg pre-zeroed)
// ---------------------------------------------------------------------------
__global__ __launch_bounds__(256) void prep_kernel(
    const float* __restrict__ x,
    const float* __restrict__ vis0, const float* __restrict__ vis1,
    const int* __restrict__ ei0, const int* __restrict__ ei1,
    const float* __restrict__ W_in1, const float* __restrict__ b_in1,
    const float* __restrict__ bn_gamma, const float* __restrict__ bn_beta,
    const float* __restrict__ bn_mean, const float* __restrict__ bn_var,
    const float* __restrict__ prelu_a,
    const float* __restrict__ W_in2, const float* __restrict__ b_in2,
    const float* __restrict__ w_node, const float* __restrict__ b_node,
    const float* __restrict__ W_c0, const float* __restrict__ b_c0,
    const float* __restrict__ W_c1, const float* __restrict__ b_c1,
    const float* __restrict__ w_p0, const float* __restrict__ b_p0,
    const float* __restrict__ w_p1, const float* __restrict__ b_p1,
    float* __restrict__ out, float* __restrict__ p0w, float* __restrict__ p1w,
    unsigned short* __restrict__ vn0, unsigned short* __restrict__ vn1,
    int* __restrict__ deg0, int* __restrict__ deg1)
{
    const int bid = blockIdx.x;
    const int t   = threadIdx.x;

    if (bid < NODE_BLOCKS) {
        __shared__ float sW1[9 * H];
        __shared__ float sW2[H * H];
        __shared__ float sU0[H], sU1[H], sWn[H];
        __shared__ float sB1[H], sB2[H], sSc[H], sSh[H];
        __shared__ float sC;

        for (int i = t; i < 9 * H; i += 256) sW1[i] = W_in1[i];
        for (int i = t; i < H * H; i += 256) sW2[i] = W_in2[i];
        if (t < H) {
            sB1[t] = b_in1[t];
            sB2[t] = b_in2[t];
            float sc = bn_gamma[t] * rsqrtf(bn_var[t] + 1e-5f);
            sSc[t] = sc;
            sSh[t] = bn_beta[t] - bn_mean[t] * sc;
            sWn[t] = w_node[t];
            float u0 = 0.f, u1 = 0.f;
            for (int j = 0; j < H; j++) {
                u0 += W_c0[t * H + j] * w_p0[j];
                u1 += W_c1[t * H + j] * w_p1[j];
            }
            sU0[t] = u0; sU1[t] = u1;
        }
        if (t == 0) {
            float c0 = b_p0[0], c1 = b_p1[0];
            for (int j = 0; j < H; j++) { c0 += b_c0[j] * w_p0[j]; c1 += b_c1[j] * w_p1[j]; }
            sC = c0 + c1 + b_node[0];
        }
        __syncthreads();

        const float a = prelu_a[0];
        const int n = bid * 256 + t;
        if (n >= N_NODES) return;

        float xi[9];
        #pragma unroll
        for (int i = 0; i < 9; i++) xi[i] = x[n * 9 + i];

        float tt[H];
        #pragma unroll
        for (int j = 0; j < H; j++) {
            float s = sB1[j];
            #pragma unroll
            for (int i = 0; i < 9; i++) s += xi[i] * sW1[i * H + j];
            s = s * sSc[j] + sSh[j];
            tt[j] = s >= 0.f ? s : a * s;
        }

        float ns = 0.f, p0 = 0.f, p1 = 0.f;
        #pragma unroll
        for (int k = 0; k < H; k++) {
            float h = sB2[k];
            #pragma unroll
            for (int j = 0; j < H; j++) h += tt[j] * sW2[j * H + k];
            ns += h * sWn[k];
            p0 += h * sU0[k];
            p1 += h * sU1[k];
        }
        out[n] = ns + sC;
        p0w[n] = p0;
        p1w[n] = p1;
    } else if (bid < NODE_BLOCKS + NC_BLOCKS) {
        const int node = ((bid - NODE_BLOCKS) * 256 + t) >> 6;
        if (node < N_NODES) normconv_node<VD0>(vis0, vn0, node, t & 63);
    } else if (bid < NODE_BLOCKS + 2 * NC_BLOCKS) {
        const int node = ((bid - NODE_BLOCKS - NC_BLOCKS) * 256 + t) >> 6;
        if (node < N_NODES) normconv_node<VD1>(vis1, vn1, node, t & 63);
    } else {
        const int e = (bid - NODE_BLOCKS - 2 * NC_BLOCKS) * 256 + t;
        if (e < NE) {
            atomicAdd(&deg0[ei0[NE + e]], 1);
            atomicAdd(&deg1[ei1[NE + e]], 1);
        }
    }
}

// ---------------------------------------------------------------------------
// Exclusive scan over degrees (both graphs in one dispatch: grid = 2)
// ---------------------------------------------------------------------------
__global__ __launch_bounds__(1024) void scan_kernel(
    const int* __restrict__ deg0, int* __restrict__ row0, int* __restrict__ cur0,
    const int* __restrict__ deg1, int* __restrict__ row1, int* __restrict__ cur1)
{
    const int* deg = blockIdx.x ? deg1 : deg0;
    int* row_start = blockIdx.x ? row1 : row0;
    int* cursor    = blockIdx.x ? cur1 : cur0;

    __shared__ int s[1024];
    const int t = threadIdx.x;
    const int base = t * 10;
    int local[10];
    int sum = 0;
    #pragma unroll
    for (int k = 0; k < 10; k++) {
        int v = (base + k < N_NODES) ? deg[base + k] : 0;
        local[k] = v;
        sum += v;
    }
    s[t] = sum;
    __syncthreads();
    for (int off = 1; off < 1024; off <<= 1) {
        int v = 0;
        if (t >= off) v = s[t - off];
        __syncthreads();
        if (t >= off) s[t] += v;
        __syncthreads();
    }
    int excl = s[t] - sum;
    #pragma unroll
    for (int k = 0; k < 10; k++) {
        if (base + k < N_NODES) {
            row_start[base + k] = excl;
            cursor[base + k] = excl;
            excl += local[k];
        }
    }
    if (t == 1023) row_start[N_NODES] = s[1023];
}

// ---------------------------------------------------------------------------
// Scatter src indices into CSR order (both graphs, one dispatch)
// ---------------------------------------------------------------------------
__global__ __launch_bounds__(256) void scatter_kernel(
    const int* __restrict__ ei0, int* __restrict__ cur0, int* __restrict__ csr0,
    const int* __restrict__ ei1, int* __restrict__ cur1, int* __restrict__ csr1)
{
    const int e = blockIdx.x * 256 + threadIdx.x;
    if (e < NE) {
        int d = ei0[NE + e];
        csr0[atomicAdd(&cur0[d], 1)] = ei0[e];
        d = ei1[NE + e];
        csr1[atomicAdd(&cur1[d], 1)] = ei1[e];
    }
}

// ---------------------------------------------------------------------------
// Fused edge kernel (block-range dispatch):
//  graph0 [0, 10000):  phase-major K-chunking (4 phases x 512 elems, uint4).
//                      Wave per dst. 8-edge unroll: indices+payloads
//                      prefetched, then 8 independent 1KB row loads in
//                      flight (MLP attack on the request path).
//  graph1 [10000,12500): 4 dsts per block, one wave per dst (uint2/lane).
// ---------------------------------------------------------------------------
__global__ __launch_bounds__(256) void edge_kernel_fused(
    const unsigned short* __restrict__ vn0,
    const int* __restrict__ row0, const int* __restrict__ csr0,
    const float* __restrict__ p0w,
    const unsigned short* __restrict__ vn1,
    const int* __restrict__ row1, const int* __restrict__ csr1,
    const float* __restrict__ p1w,
    float* __restrict__ out)
{
    const int bid  = blockIdx.x;
    const int lane = threadIdx.x & 63;

    if (bid < EDGE0_BLOCKS) {
        const int phase = bid / EDGE0_GBLK;
        const int group = bid % EDGE0_GBLK;
        const int d     = group * 4 + (threadIdx.x >> 6);
        const int beg = row0[d];
        const int end = row0[d + 1];
        if (beg == end) return;

        // byte base for this phase+lane (row stride = VD0*2 = 4096 B)
        const char* vb = (const char*)vn0 + (size_t)phase * 1024 + (size_t)lane * 16;
        const uint4 dreg = *(const uint4*)(vb + ((size_t)d << 12));

        float partial = 0.f;
        int j = beg;
        for (; j + 7 < end; j += 8) {
            int  si[8];
            #pragma unroll
            for (int k = 0; k < 8; k++) si[k] = csr0[j + k];
            float pv[8];
            #pragma unroll
            for (int k = 0; k < 8; k++) pv[k] = p0w[si[k]];
            uint4 r[8];
            #pragma unroll
            for (int k = 0; k < 8; k++) r[k] = *(const uint4*)(vb + ((size_t)si[k] << 12));
            #pragma unroll
            for (int k = 0; k < 8; k++) partial += dot8_bf16(dreg, r[k]) * pv[k];
        }
        if (j + 3 < end) {
            int  si[4];
            #pragma unroll
            for (int k = 0; k < 4; k++) si[k] = csr0[j + k];
            float pv[4];
            #pragma unroll
            for (int k = 0; k < 4; k++) pv[k] = p0w[si[k]];
            uint4 r[4];
            #pragma unroll
            for (int k = 0; k < 4; k++) r[k] = *(const uint4*)(vb + ((size_t)si[k] << 12));
            #pragma unroll
            for (int k = 0; k < 4; k++) partial += dot8_bf16(dreg, r[k]) * pv[k];
            j += 4;
        }
        for (; j < end; j++) {
            const int s0 = csr0[j];
            const uint4 r0 = *(const uint4*)(vb + ((size_t)s0 << 12));
            partial += dot8_bf16(dreg, r0) * p0w[s0];
        }
        #pragma unroll
        for (int o = 32; o; o >>= 1) partial += __shfl_down(partial, o);
        if (lane == 0) atomicAdd(&out[d], partial);
    } else {
        const int d = (bid - EDGE0_BLOCKS) * 4 + (threadIdx.x >> 6);
        const int beg = row1[d];
        const int end = row1[d + 1];
        if (beg == end) return;
        const char* vb = (const char*)vn1 + (size_t)lane * 8;   // row stride 512 B
        const uint2 dreg = *(const uint2*)(vb + ((size_t)d << 9));
        float partial = 0.f;
        int j = beg;
        for (; j + 7 < end; j += 8) {
            int  si[8];
            #pragma unroll
            for (int k = 0; k < 8; k++) si[k] = csr1[j + k];
            float pv[8];
            #pragma unroll
            for (int k = 0; k < 8; k++) pv[k] = p1w[si[k]];
            uint2 r[8];
            #pragma unroll
            for (int k = 0; k < 8; k++) r[k] = *(const uint2*)(vb + ((size_t)si[k] << 9));
            #pragma unroll
            for (int k = 0; k < 8; k++) partial += dot4_bf16(dreg, r[k]) * pv[k];
        }
        for (; j < end; j++) {
            const int s0 = csr1[j];
            const uint2 r0 = *(const uint2*)(vb + ((size_t)s0 << 9));
            partial += dot4_bf16(dreg, r0) * p1w[s0];
        }
        #pragma unroll
        for (int o = 32; o; o >>= 1) partial += __shfl_down(partial, o);
        if (lane == 0) atomicAdd(&out[d], partial);
    }
}

// ---------------------------------------------------------------------------
// fp32 fallback (only if ws can't hold bf16 rows + CSR)
// ---------------------------------------------------------------------------
template <int VD>
__global__ __launch_bounds__(256) void norm_kernel(const float* __restrict__ vis,
                                                   float* __restrict__ inv)
{
    const int wave = (blockIdx.x * 256 + threadIdx.x) >> 6;
    const int lane = threadIdx.x & 63;
    if (wave >= N_NODES) return;
    const float4* v = (const float4*)(vis + (size_t)wave * VD);
    float acc = 0.f;
    #pragma unroll
    for (int it = 0; it < VD / 256; it++) {
        float4 f = v[lane + it * 64];
        acc += f.x * f.x + f.y * f.y + f.z * f.z + f.w * f.w;
    }
    #pragma unroll
    for (int o = 32; o; o >>= 1) acc += __shfl_down(acc, o);
    if (lane == 0) inv[wave] = rsqrtf(acc + 1e-8f);
}

template <int VD>
__global__ __launch_bounds__(256) void edge_kernel(
    const float* __restrict__ vis, const int* __restrict__ ei,
    const float* __restrict__ inv, const float* __restrict__ p,
    float* __restrict__ out)
{
    const int wave = (blockIdx.x * 256 + threadIdx.x) >> 6;
    const int lane = threadIdx.x & 63;
    if (wave >= NE) return;
    const int src = ei[wave];
    const int dst = ei[NE + wave];
    const float4* va = (const float4*)(vis + (size_t)src * VD);
    const float4* vb = (const float4*)(vis + (size_t)dst * VD);
    float acc = 0.f;
    #pragma unroll
    for (int it = 0; it < VD / 256; it++) {
        float4 fa = va[lane + it * 64];
        float4 fb = vb[lane + it * 64];
        acc += fa.x * fb.x + fa.y * fb.y + fa.z * fb.z + fa.w * fb.w;
    }
    #pragma unroll
    for (int o = 32; o; o >>= 1) acc += __shfl_down(acc, o);
    if (lane == 0) {
        float w = acc * inv[src] * inv[dst];
        atomicAdd(&out[dst], w * p[src]);
    }
}

__global__ __launch_bounds__(256) void node_kernel_fb(
    const float* __restrict__ x,
    const float* __restrict__ W_in1, const float* __restrict__ b_in1,
    const float* __restrict__ bn_gamma, const float* __restrict__ bn_beta,
    const float* __restrict__ bn_mean, const float* __restrict__ bn_var,
    const float* __restrict__ prelu_a,
    const float* __restrict__ W_in2, const float* __restrict__ b_in2,
    const float* __restrict__ w_node, const float* __restrict__ b_node,
    const float* __restrict__ W_c0, const float* __restrict__ b_c0,
    const float* __restrict__ W_c1, const float* __restrict__ b_c1,
    const float* __restrict__ w_p0, const float* __restrict__ b_p0,
    const float* __restrict__ w_p1, const float* __restrict__ b_p1,
    float* __restrict__ out, float* __restrict__ p0w, float* __restrict__ p1w)
{
    __shared__ float sW1[9 * H];
    __shared__ float sW2[H * H];
    __shared__ float sU0[H], sU1[H], sWn[H];
    __shared__ float sB1[H], sB2[H], sSc[H], sSh[H];
    __shared__ float sC;

    const int t = threadIdx.x;
    for (int i = t; i < 9 * H; i += 256) sW1[i] = W_in1[i];
    for (int i = t; i < H * H; i += 256) sW2[i] = W_in2[i];
    if (t < H) {
        sB1[t] = b_in1[t];
        sB2[t] = b_in2[t];
        float sc = bn_gamma[t] * rsqrtf(bn_var[t] + 1e-5f);
        sSc[t] = sc;
        sSh[t] = bn_beta[t] - bn_mean[t] * sc;
        sWn[t] = w_node[t];
        float u0 = 0.f, u1 = 0.f;
        for (int j = 0; j < H; j++) {
            u0 += W_c0[t * H + j] * w_p0[j];
            u1 += W_c1[t * H + j] * w_p1[j];
        }
        sU0[t] = u0; sU1[t] = u1;
    }
    if (t == 0) {
        float c0 = b_p0[0], c1 = b_p1[0];
        for (int j = 0; j < H; j++) { c0 += b_c0[j] * w_p0[j]; c1 += b_c1[j] * w_p1[j]; }
        sC = c0 + c1 + b_node[0];
    }
    __syncthreads();

    const float a = prelu_a[0];
    const int n = blockIdx.x * 256 + t;
    if (n >= N_NODES) return;

    float xi[9];
    #pragma unroll
    for (int i = 0; i < 9; i++) xi[i] = x[n * 9 + i];

    float tt[H];
    #pragma unroll
    for (int j = 0; j < H; j++) {
        float s = sB1[j];
        #pragma unroll
        for (int i = 0; i < 9; i++) s += xi[i] * sW1[i * H + j];
        s = s * sSc[j] + sSh[j];
        tt[j] = s >= 0.f ? s : a * s;
    }

    float ns = 0.f, p0 = 0.f, p1 = 0.f;
    #pragma unroll
    for (int k = 0; k < H; k++) {
        float h = sB2[k];
        #pragma unroll
        for (int j = 0; j < H; j++) h += tt[j] * sW2[j * H + k];
        ns += h * sWn[k];
        p0 += h * sU0[k];
        p1 += h * sU1[k];
    }
    out[n] = ns + sC;
    p0w[n] = p0;
    p1w[n] = p1;
}

extern "C" void kernel_launch(void* const* d_in, const int* in_sizes, int n_in,
                              void* d_out, int out_size, void* d_ws, size_t ws_size,
                              hipStream_t stream)
{
    const float* x        = (const float*)d_in[0];
    const float* vis0     = (const float*)d_in[1];
    const float* vis1     = (const float*)d_in[2];
    const int*   ei0      = (const int*)d_in[3];
    const int*   ei1      = (const int*)d_in[4];
    const float* W_in1    = (const float*)d_in[5];
    const float* b_in1    = (const float*)d_in[6];
    const float* bn_gamma = (const float*)d_in[7];
    const float* bn_beta  = (const float*)d_in[8];
    const float* bn_mean  = (const float*)d_in[9];
    const float* bn_var   = (const float*)d_in[10];
    const float* prelu_a  = (const float*)d_in[11];
    const float* W_in2    = (const float*)d_in[12];
    const float* b_in2    = (const float*)d_in[13];
    const float* w_node   = (const float*)d_in[14];
    const float* b_node   = (const float*)d_in[15];
    const float* W_c0     = (const float*)d_in[16];
    const float* b_c0     = (const float*)d_in[17];
    const float* W_c1     = (const float*)d_in[18];
    const float* b_c1     = (const float*)d_in[19];
    const float* w_p0     = (const float*)d_in[20];
    const float* b_p0     = (const float*)d_in[21];
    const float* w_p1     = (const float*)d_in[22];
    const float* b_p1     = (const float*)d_in[23];

    float* out = (float*)d_out;

    // workspace layout
    char* ws = (char*)d_ws;
    float* p0w  = (float*)ws;                  ws += N_NODES * 4;
    float* p1w  = (float*)ws;                  ws += N_NODES * 4;
    float* inv0 = (float*)ws;                  ws += N_NODES * 4;
    float* inv1 = (float*)ws;                  ws += N_NODES * 4;
    int* deg0       = (int*)ws;                ws += N_NODES * 4;      // deg0+deg1 contiguous
    int* deg1       = (int*)ws;                ws += N_NODES * 4;      //   (single memset)
    int* row0       = (int*)ws;                ws += (N_NODES + 1) * 4;
    int* row1       = (int*)ws;                ws += (N_NODES + 1) * 4;
    int* cur0       = (int*)ws;                ws += N_NODES * 4;
    int* cur1       = (int*)ws;                ws += N_NODES * 4;
    int* csr0       = (int*)ws;                ws += NE * 4;
    int* csr1       = (int*)ws;                ws += NE * 4;
    unsigned short* vn0 = (unsigned short*)ws; ws += (size_t)N_NODES * VD0 * 2;
    unsigned short* vn1 = (unsigned short*)ws; ws += (size_t)N_NODES * VD1 * 2;
    const size_t need = (size_t)(ws - (char*)d_ws);

    if (ws_size >= need) {
        hipMemsetAsync(deg0, 0, 2 * N_NODES * sizeof(int), stream);

        prep_kernel<<<PREP_BLOCKS, 256, 0, stream>>>(
            x, vis0, vis1, ei0, ei1,
            W_in1, b_in1, bn_gamma, bn_beta, bn_mean, bn_var, prelu_a,
            W_in2, b_in2, w_node, b_node, W_c0, b_c0, W_c1, b_c1,
            w_p0, b_p0, w_p1, b_p1,
            out, p0w, p1w, vn0, vn1, deg0, deg1);

        scan_kernel<<<2, 1024, 0, stream>>>(deg0, row0, cur0, deg1, row1, cur1);

        scatter_kernel<<<(NE + 255) / 256, 256, 0, stream>>>(
            ei0, cur0, csr0, ei1, cur1, csr1);

        edge_kernel_fused<<<EDGE_BLOCKS, 256, 0, stream>>>(
            vn0, row0, csr0, p0w, vn1, row1, csr1, p1w, out);
    } else {
        node_kernel_fb<<<(N_NODES + 255) / 256, 256, 0, stream>>>(
            x, W_in1, b_in1, bn_gamma, bn_beta, bn_mean, bn_var, prelu_a,
            W_in2, b_in2, w_node, b_node, W_c0, b_c0, W_c1, b_c1,
            w_p0, b_p0, w_p1, b_p1, out, p0w, p1w);
        norm_kernel<VD0><<<(N_NODES * 64 + 255) / 256, 256, 0, stream>>>(vis0, inv0);
        norm_kernel<VD1><<<(N_NODES * 64 + 255) / 256, 256, 0, stream>>>(vis1, inv1);
        edge_kernel<VD0><<<(NE * 64 + 255) / 256, 256, 0, stream>>>(vis0, ei0, inv0, p0w, out);
        edge_kernel<VD1><<<(NE * 64 + 255) / 256, 256, 0, stream>>>(vis1, ei1, inv1, p1w, out);
    }
}

// Round 8
// 254.806 us; speedup vs baseline: 1.0405x; 1.0405x over previous
//
#include <hip/hip_runtime.h>

#define N_NODES 10000
#define NE      80000
#define H       32
#define VD0     2048
#define VD1     256

// prep kernel block-range dispatch
#define NODE_BLOCKS  40                    // (N_NODES+255)/256
#define NC_BLOCKS    2500                  // wave per node (4 waves/block)
#define HIST_BLOCKS  313                   // (NE+255)/256
#define PREP_BLOCKS  (NODE_BLOCKS + 2 * NC_BLOCKS + HIST_BLOCKS)

// fused edge kernel block-range dispatch
// graph0: 4 K-phases (512-elem chunks, uint4/lane); within a phase, wave per
// dst, 4-edge unroll. Best measured config (R5: 53.2 us, total 255.6 us).
#define EDGE0_PHASES  4
#define EDGE0_GBLK    2500                 // dst-groups per phase (4 dsts/block)
#define EDGE0_BLOCKS  (EDGE0_PHASES * EDGE0_GBLK)
#define EDGE1_BLOCKS  2500                 // graph1: 4 dsts per block, wave per dst
#define EDGE_BLOCKS   (EDGE0_BLOCKS + EDGE1_BLOCKS)

// ---------------------------------------------------------------------------
// bf16 helpers
// ---------------------------------------------------------------------------
__device__ inline unsigned short f2bf_rne(float f) {
    unsigned int u = __float_as_uint(f);
    u += 0x7fffu + ((u >> 16) & 1u);
    return (unsigned short)(u >> 16);
}
__device__ inline float bflo(unsigned int u) { return __uint_as_float(u << 16); }
__device__ inline float bfhi(unsigned int u) { return __uint_as_float(u & 0xffff0000u); }

__device__ inline float dot8_bf16(uint4 a, uint4 b) {
    float s;
    s  = bflo(a.x) * bflo(b.x) + bfhi(a.x) * bfhi(b.x);
    s += bflo(a.y) * bflo(b.y) + bfhi(a.y) * bfhi(b.y);
    s += bflo(a.z) * bflo(b.z) + bfhi(a.z) * bfhi(b.z);
    s += bflo(a.w) * bflo(b.w) + bfhi(a.w) * bfhi(b.w);
    return s;
}
__device__ inline float dot4_bf16(uint2 a, uint2 b) {
    return bflo(a.x) * bflo(b.x) + bfhi(a.x) * bfhi(b.x)
         + bflo(a.y) * bflo(b.y) + bfhi(a.y) * bfhi(b.y);
}

// ---------------------------------------------------------------------------
// normconv body: vn[node] = bf16( vis[node] * rsqrt(||vis[node]||^2 + 1e-8) )
// one 64-lane wave per node, row held in registers between passes
// ---------------------------------------------------------------------------
template <int VD>
__device__ inline void normconv_node(const float* __restrict__ vis,
                                     unsigned short* __restrict__ vn,
                                     int node, int lane)
{
    const float4* v = (const float4*)(vis + (size_t)node * VD);
    float4 f[VD / 256];
    float acc = 0.f;
    #pragma unroll
    for (int it = 0; it < VD / 256; it++) {
        f[it] = v[it * 64 + lane];
        acc += f[it].x * f[it].x + f[it].y * f[it].y + f[it].z * f[it].z + f[it].w * f[it].w;
    }
    #pragma unroll
    for (int o = 32; o; o >>= 1) acc += __shfl_xor(acc, o);
    const float inv = rsqrtf(acc + 1e-8f);
    ushort4* o4 = (ushort4*)(vn + (size_t)node * VD);
    #pragma unroll
    for (int it = 0; it < VD / 256; it++) {
        ushort4 r;
        r.x = f2bf_rne(f[it].x * inv);
        r.y = f2bf_rne(f[it].y * inv);
        r.z = f2bf_rne(f[it].z * inv);
        r.w = f2bf_rne(f[it].w * inv);
        o4[it * 64 + lane] = r;
    }
}

// ---------------------------------------------------------------------------
// PREP mega-kernel (block-range dispatch, all paths independent):
//   [0, 40)          node MLP + head folding -> out, p0w, p1w
//   [40, 2540)       normconv graph0 (VD0)
//   [2540, 5040)     normconv graph1 (VD1)
//   [5040, 5353)     dst-degree histograms for both graphs (deg pre-zeroed)
// ---------------------------------------------------------------------------
__global__ __launch_bounds__(256) void prep_kernel(
    const float* __restrict__ x,
    const float* __restrict__ vis0, const float* __restrict__ vis1,
    const int* __restrict__ ei0, const int* __restrict__ ei1,
    const float* __restrict__ W_in1, const float* __restrict__ b_in1,
    const float* __restrict__ bn_gamma, const float* __restrict__ bn_beta,
    const float* __restrict__ bn_mean, const float* __restrict__ bn_var,
    const float* __restrict__ prelu_a,
    const float* __restrict__ W_in2, const float* __restrict__ b_in2,
    const float* __restrict__ w_node, const float* __restrict__ b_node,
    const float* __restrict__ W_c0, const float* __restrict__ b_c0,
    const float* __restrict__ W_c1, const float* __restrict__ b_c1,
    const float* __restrict__ w_p0, const float* __restrict__ b_p0,
    const float* __restrict__ w_p1, const float* __restrict__ b_p1,
    float* __restrict__ out, float* __restrict__ p0w, float* __restrict__ p1w,
    unsigned short* __restrict__ vn0, unsigned short* __restrict__ vn1,
    int* __restrict__ deg0, int* __restrict__ deg1)
{
    const int bid = blockIdx.x;
    const int t   = threadIdx.x;

    if (bid < NODE_BLOCKS) {
        // ---- node MLP path ----
        __shared__ float sW1[9 * H];
        __shared__ float sW2[H * H];
        __shared__ float sU0[H], sU1[H], sWn[H];
        __shared__ float sB1[H], sB2[H], sSc[H], sSh[H];
        __shared__ float sC;

        for (int i = t; i < 9 * H; i += 256) sW1[i] = W_in1[i];
        for (int i = t; i < H * H; i += 256) sW2[i] = W_in2[i];
        if (t < H) {
            sB1[t] = b_in1[t];
            sB2[t] = b_in2[t];
            float sc = bn_gamma[t] * rsqrtf(bn_var[t] + 1e-5f);
            sSc[t] = sc;
            sSh[t] = bn_beta[t] - bn_mean[t] * sc;
            sWn[t] = w_node[t];
            float u0 = 0.f, u1 = 0.f;
            for (int j = 0; j < H; j++) {
                u0 += W_c0[t * H + j] * w_p0[j];
                u1 += W_c1[t * H + j] * w_p1[j];
            }
            sU0[t] = u0; sU1[t] = u1;
        }
        if (t == 0) {
            float c0 = b_p0[0], c1 = b_p1[0];
            for (int j = 0; j < H; j++) { c0 += b_c0[j] * w_p0[j]; c1 += b_c1[j] * w_p1[j]; }
            sC = c0 + c1 + b_node[0];
        }
        __syncthreads();

        const float a = prelu_a[0];
        const int n = bid * 256 + t;
        if (n >= N_NODES) return;

        float xi[9];
        #pragma unroll
        for (int i = 0; i < 9; i++) xi[i] = x[n * 9 + i];

        float tt[H];
        #pragma unroll
        for (int j = 0; j < H; j++) {
            float s = sB1[j];
            #pragma unroll
            for (int i = 0; i < 9; i++) s += xi[i] * sW1[i * H + j];
            s = s * sSc[j] + sSh[j];
            tt[j] = s >= 0.f ? s : a * s;
        }

        float ns = 0.f, p0 = 0.f, p1 = 0.f;
        #pragma unroll
        for (int k = 0; k < H; k++) {
            float h = sB2[k];
            #pragma unroll
            for (int j = 0; j < H; j++) h += tt[j] * sW2[j * H + k];
            ns += h * sWn[k];
            p0 += h * sU0[k];
            p1 += h * sU1[k];
        }
        out[n] = ns + sC;
        p0w[n] = p0;
        p1w[n] = p1;
    } else if (bid < NODE_BLOCKS + NC_BLOCKS) {
        const int node = ((bid - NODE_BLOCKS) * 256 + t) >> 6;
        if (node < N_NODES) normconv_node<VD0>(vis0, vn0, node, t & 63);
    } else if (bid < NODE_BLOCKS + 2 * NC_BLOCKS) {
        const int node = ((bid - NODE_BLOCKS - NC_BLOCKS) * 256 + t) >> 6;
        if (node < N_NODES) normconv_node<VD1>(vis1, vn1, node, t & 63);
    } else {
        const int e = (bid - NODE_BLOCKS - 2 * NC_BLOCKS) * 256 + t;
        if (e < NE) {
            atomicAdd(&deg0[ei0[NE + e]], 1);
            atomicAdd(&deg1[ei1[NE + e]], 1);
        }
    }
}

// ---------------------------------------------------------------------------
// Exclusive scan over degrees (both graphs in one dispatch: grid = 2)
// ---------------------------------------------------------------------------
__global__ __launch_bounds__(1024) void scan_kernel(
    const int* __restrict__ deg0, int* __restrict__ row0, int* __restrict__ cur0,
    const int* __restrict__ deg1, int* __restrict__ row1, int* __restrict__ cur1)
{
    const int* deg = blockIdx.x ? deg1 : deg0;
    int* row_start = blockIdx.x ? row1 : row0;
    int* cursor    = blockIdx.x ? cur1 : cur0;

    __shared__ int s[1024];
    const int t = threadIdx.x;
    const int base = t * 10;
    int local[10];
    int sum = 0;
    #pragma unroll
    for (int k = 0; k < 10; k++) {
        int v = (base + k < N_NODES) ? deg[base + k] : 0;
        local[k] = v;
        sum += v;
    }
    s[t] = sum;
    __syncthreads();
    for (int off = 1; off < 1024; off <<= 1) {
        int v = 0;
        if (t >= off) v = s[t - off];
        __syncthreads();
        if (t >= off) s[t] += v;
        __syncthreads();
    }
    int excl = s[t] - sum;
    #pragma unroll
    for (int k = 0; k < 10; k++) {
        if (base + k < N_NODES) {
            row_start[base + k] = excl;
            cursor[base + k] = excl;
            excl += local[k];
        }
    }
    if (t == 1023) row_start[N_NODES] = s[1023];
}

// ---------------------------------------------------------------------------
// Scatter src indices into CSR order (both graphs, one dispatch)
// ---------------------------------------------------------------------------
__global__ __launch_bounds__(256) void scatter_kernel(
    const int* __restrict__ ei0, int* __restrict__ cur0, int* __restrict__ csr0,
    const int* __restrict__ ei1, int* __restrict__ cur1, int* __restrict__ csr1)
{
    const int e = blockIdx.x * 256 + threadIdx.x;
    if (e < NE) {
        int d = ei0[NE + e];
        csr0[atomicAdd(&cur0[d], 1)] = ei0[e];
        d = ei1[NE + e];
        csr1[atomicAdd(&cur1[d], 1)] = ei1[e];
    }
}

// ---------------------------------------------------------------------------
// Fused edge kernel (block-range dispatch):
//  graph0 [0, 10000):  phase-major K-chunking. phase = bid/2500 selects a
//                      512-elem chunk of the 2048-dim rows; within a phase,
//                      wave per dst (uint4/lane), 4-edge unroll. Partial dot
//                      per (dst,chunk), one atomicAdd each.
//  graph1 [10000,12500): 4 dsts per block, one wave per dst (uint2/lane).
// ---------------------------------------------------------------------------
__global__ __launch_bounds__(256) void edge_kernel_fused(
    const unsigned short* __restrict__ vn0,
    const int* __restrict__ row0, const int* __restrict__ csr0,
    const float* __restrict__ p0w,
    const unsigned short* __restrict__ vn1,
    const int* __restrict__ row1, const int* __restrict__ csr1,
    const float* __restrict__ p1w,
    float* __restrict__ out)
{
    const int bid  = blockIdx.x;
    const int lane = threadIdx.x & 63;

    if (bid < EDGE0_BLOCKS) {
        const int phase = bid / EDGE0_GBLK;          // 512-elem chunk index
        const int group = bid % EDGE0_GBLK;
        const int d     = group * 4 + (threadIdx.x >> 6);
        const int koff  = phase * 512;               // element offset into row
        const int beg = row0[d];
        const int end = row0[d + 1];
        if (beg == end) return;

        const uint4 dreg = ((const uint4*)(vn0 + (size_t)d * VD0 + koff))[lane];
        float partial = 0.f;
        int j = beg;
        for (; j + 3 < end; j += 4) {
            const int s0 = csr0[j], s1 = csr0[j + 1], s2 = csr0[j + 2], s3 = csr0[j + 3];
            const uint4 r0 = ((const uint4*)(vn0 + (size_t)s0 * VD0 + koff))[lane];
            const uint4 r1 = ((const uint4*)(vn0 + (size_t)s1 * VD0 + koff))[lane];
            const uint4 r2 = ((const uint4*)(vn0 + (size_t)s2 * VD0 + koff))[lane];
            const uint4 r3 = ((const uint4*)(vn0 + (size_t)s3 * VD0 + koff))[lane];
            partial += dot8_bf16(dreg, r0) * p0w[s0];
            partial += dot8_bf16(dreg, r1) * p0w[s1];
            partial += dot8_bf16(dreg, r2) * p0w[s2];
            partial += dot8_bf16(dreg, r3) * p0w[s3];
        }
        for (; j < end; j++) {
            const int s0 = csr0[j];
            const uint4 r0 = ((const uint4*)(vn0 + (size_t)s0 * VD0 + koff))[lane];
            partial += dot8_bf16(dreg, r0) * p0w[s0];
        }
        #pragma unroll
        for (int o = 32; o; o >>= 1) partial += __shfl_down(partial, o);
        if (lane == 0) atomicAdd(&out[d], partial);
    } else {
        const int d = (bid - EDGE0_BLOCKS) * 4 + (threadIdx.x >> 6);
        const int beg = row1[d];
        const int end = row1[d + 1];
        if (beg == end) return;
        const uint2 dreg = ((const uint2*)(vn1 + (size_t)d * VD1))[lane];
        float partial = 0.f;
        int j = beg;
        for (; j + 3 < end; j += 4) {
            const int s0 = csr1[j], s1 = csr1[j + 1], s2 = csr1[j + 2], s3 = csr1[j + 3];
            const uint2 r0 = ((const uint2*)(vn1 + (size_t)s0 * VD1))[lane];
            const uint2 r1 = ((const uint2*)(vn1 + (size_t)s1 * VD1))[lane];
            const uint2 r2 = ((const uint2*)(vn1 + (size_t)s2 * VD1))[lane];
            const uint2 r3 = ((const uint2*)(vn1 + (size_t)s3 * VD1))[lane];
            partial += dot4_bf16(dreg, r0) * p1w[s0];
            partial += dot4_bf16(dreg, r1) * p1w[s1];
            partial += dot4_bf16(dreg, r2) * p1w[s2];
            partial += dot4_bf16(dreg, r3) * p1w[s3];
        }
        for (; j < end; j++) {
            const int s0 = csr1[j];
            const uint2 r0 = ((const uint2*)(vn1 + (size_t)s0 * VD1))[lane];
            partial += dot4_bf16(dreg, r0) * p1w[s0];
        }
        #pragma unroll
        for (int o = 32; o; o >>= 1) partial += __shfl_down(partial, o);
        if (lane == 0) atomicAdd(&out[d], partial);
    }
}

// ---------------------------------------------------------------------------
// fp32 fallback (only if ws can't hold bf16 rows + CSR)
// ---------------------------------------------------------------------------
template <int VD>
__global__ __launch_bounds__(256) void norm_kernel(const float* __restrict__ vis,
                                                   float* __restrict__ inv)
{
    const int wave = (blockIdx.x * 256 + threadIdx.x) >> 6;
    const int lane = threadIdx.x & 63;
    if (wave >= N_NODES) return;
    const float4* v = (const float4*)(vis + (size_t)wave * VD);
    float acc = 0.f;
    #pragma unroll
    for (int it = 0; it < VD / 256; it++) {
        float4 f = v[lane + it * 64];
        acc += f.x * f.x + f.y * f.y + f.z * f.z + f.w * f.w;
    }
    #pragma unroll
    for (int o = 32; o; o >>= 1) acc += __shfl_down(acc, o);
    if (lane == 0) inv[wave] = rsqrtf(acc + 1e-8f);
}

template <int VD>
__global__ __launch_bounds__(256) void edge_kernel(
    const float* __restrict__ vis, const int* __restrict__ ei,
    const float* __restrict__ inv, const float* __restrict__ p,
    float* __restrict__ out)
{
    const int wave = (blockIdx.x * 256 + threadIdx.x) >> 6;
    const int lane = threadIdx.x & 63;
    if (wave >= NE) return;
    const int src = ei[wave];
    const int dst = ei[NE + wave];
    const float4* va = (const float4*)(vis + (size_t)src * VD);
    const float4* vb = (const float4*)(vis + (size_t)dst * VD);
    float acc = 0.f;
    #pragma unroll
    for (int it = 0; it < VD / 256; it++) {
        float4 fa = va[lane + it * 64];
        float4 fb = vb[lane + it * 64];
        acc += fa.x * fb.x + fa.y * fb.y + fa.z * fb.z + fa.w * fb.w;
    }
    #pragma unroll
    for (int o = 32; o; o >>= 1) acc += __shfl_down(acc, o);
    if (lane == 0) {
        float w = acc * inv[src] * inv[dst];
        atomicAdd(&out[dst], w * p[src]);
    }
}

__global__ __launch_bounds__(256) void node_kernel_fb(
    const float* __restrict__ x,
    const float* __restrict__ W_in1, const float* __restrict__ b_in1,
    const float* __restrict__ bn_gamma, const float* __restrict__ bn_beta,
    const float* __restrict__ bn_mean, const float* __restrict__ bn_var,
    const float* __restrict__ prelu_a,
    const float* __restrict__ W_in2, const float* __restrict__ b_in2,
    const float* __restrict__ w_node, const float* __restrict__ b_node,
    const float* __restrict__ W_c0, const float* __restrict__ b_c0,
    const float* __restrict__ W_c1, const float* __restrict__ b_c1,
    const float* __restrict__ w_p0, const float* __restrict__ b_p0,
    const float* __restrict__ w_p1, const float* __restrict__ b_p1,
    float* __restrict__ out, float* __restrict__ p0w, float* __restrict__ p1w)
{
    __shared__ float sW1[9 * H];
    __shared__ float sW2[H * H];
    __shared__ float sU0[H], sU1[H], sWn[H];
    __shared__ float sB1[H], sB2[H], sSc[H], sSh[H];
    __shared__ float sC;

    const int t = threadIdx.x;
    for (int i = t; i < 9 * H; i += 256) sW1[i] = W_in1[i];
    for (int i = t; i < H * H; i += 256) sW2[i] = W_in2[i];
    if (t < H) {
        sB1[t] = b_in1[t];
        sB2[t] = b_in2[t];
        float sc = bn_gamma[t] * rsqrtf(bn_var[t] + 1e-5f);
        sSc[t] = sc;
        sSh[t] = bn_beta[t] - bn_mean[t] * sc;
        sWn[t] = w_node[t];
        float u0 = 0.f, u1 = 0.f;
        for (int j = 0; j < H; j++) {
            u0 += W_c0[t * H + j] * w_p0[j];
            u1 += W_c1[t * H + j] * w_p1[j];
        }
        sU0[t] = u0; sU1[t] = u1;
    }
    if (t == 0) {
        float c0 = b_p0[0], c1 = b_p1[0];
        for (int j = 0; j < H; j++) { c0 += b_c0[j] * w_p0[j]; c1 += b_c1[j] * w_p1[j]; }
        sC = c0 + c1 + b_node[0];
    }
    __syncthreads();

    const float a = prelu_a[0];
    const int n = blockIdx.x * 256 + t;
    if (n >= N_NODES) return;

    float xi[9];
    #pragma unroll
    for (int i = 0; i < 9; i++) xi[i] = x[n * 9 + i];

    float tt[H];
    #pragma unroll
    for (int j = 0; j < H; j++) {
        float s = sB1[j];
        #pragma unroll
        for (int i = 0; i < 9; i++) s += xi[i] * sW1[i * H + j];
        s = s * sSc[j] + sSh[j];
        tt[j] = s >= 0.f ? s : a * s;
    }

    float ns = 0.f, p0 = 0.f, p1 = 0.f;
    #pragma unroll
    for (int k = 0; k < H; k++) {
        float h = sB2[k];
        #pragma unroll
        for (int j = 0; j < H; j++) h += tt[j] * sW2[j * H + k];
        ns += h * sWn[k];
        p0 += h * sU0[k];
        p1 += h * sU1[k];
    }
    out[n] = ns + sC;
    p0w[n] = p0;
    p1w[n] = p1;
}

extern "C" void kernel_launch(void* const* d_in, const int* in_sizes, int n_in,
                              void* d_out, int out_size, void* d_ws, size_t ws_size,
                              hipStream_t stream)
{
    const float* x        = (const float*)d_in[0];
    const float* vis0     = (const float*)d_in[1];
    const float* vis1     = (const float*)d_in[2];
    const int*   ei0      = (const int*)d_in[3];
    const int*   ei1      = (const int*)d_in[4];
    const float* W_in1    = (const float*)d_in[5];
    const float* b_in1    = (const float*)d_in[6];
    const float* bn_gamma = (const float*)d_in[7];
    const float* bn_beta  = (const float*)d_in[8];
    const float* bn_mean  = (const float*)d_in[9];
    const float* bn_var   = (const float*)d_in[10];
    const float* prelu_a  = (const float*)d_in[11];
    const float* W_in2    = (const float*)d_in[12];
    const float* b_in2    = (const float*)d_in[13];
    const float* w_node   = (const float*)d_in[14];
    const float* b_node   = (const float*)d_in[15];
    const float* W_c0     = (const float*)d_in[16];
    const float* b_c0     = (const float*)d_in[17];
    const float* W_c1     = (const float*)d_in[18];
    const float* b_c1     = (const float*)d_in[19];
    const float* w_p0     = (const float*)d_in[20];
    const float* b_p0     = (const float*)d_in[21];
    const float* w_p1     = (const float*)d_in[22];
    const float* b_p1     = (const float*)d_in[23];

    float* out = (float*)d_out;

    // workspace layout
    char* ws = (char*)d_ws;
    float* p0w  = (float*)ws;                  ws += N_NODES * 4;
    float* p1w  = (float*)ws;                  ws += N_NODES * 4;
    float* inv0 = (float*)ws;                  ws += N_NODES * 4;
    float* inv1 = (float*)ws;                  ws += N_NODES * 4;
    int* deg0       = (int*)ws;                ws += N_NODES * 4;      // deg0+deg1 contiguous
    int* deg1       = (int*)ws;                ws += N_NODES * 4;      //   (single memset)
    int* row0       = (int*)ws;                ws += (N_NODES + 1) * 4;
    int* row1       = (int*)ws;                ws += (N_NODES + 1) * 4;
    int* cur0       = (int*)ws;                ws += N_NODES * 4;
    int* cur1       = (int*)ws;                ws += N_NODES * 4;
    int* csr0       = (int*)ws;                ws += NE * 4;
    int* csr1       = (int*)ws;                ws += NE * 4;
    unsigned short* vn0 = (unsigned short*)ws; ws += (size_t)N_NODES * VD0 * 2;
    unsigned short* vn1 = (unsigned short*)ws; ws += (size_t)N_NODES * VD1 * 2;
    const size_t need = (size_t)(ws - (char*)d_ws);

    if (ws_size >= need) {
        hipMemsetAsync(deg0, 0, 2 * N_NODES * sizeof(int), stream);

        prep_kernel<<<PREP_BLOCKS, 256, 0, stream>>>(
            x, vis0, vis1, ei0, ei1,
            W_in1, b_in1, bn_gamma, bn_beta, bn_mean, bn_var, prelu_a,
            W_in2, b_in2, w_node, b_node, W_c0, b_c0, W_c1, b_c1,
            w_p0, b_p0, w_p1, b_p1,
            out, p0w, p1w, vn0, vn1, deg0, deg1);

        scan_kernel<<<2, 1024, 0, stream>>>(deg0, row0, cur0, deg1, row1, cur1);

        scatter_kernel<<<(NE + 255) / 256, 256, 0, stream>>>(
            ei0, cur0, csr0, ei1, cur1, csr1);

        edge_kernel_fused<<<EDGE_BLOCKS, 256, 0, stream>>>(
            vn0, row0, csr0, p0w, vn1, row1, csr1, p1w, out);
    } else {
        node_kernel_fb<<<(N_NODES + 255) / 256, 256, 0, stream>>>(
            x, W_in1, b_in1, bn_gamma, bn_beta, bn_mean, bn_var, prelu_a,
            W_in2, b_in2, w_node, b_node, W_c0, b_c0, W_c1, b_c1,
            w_p0, b_p0, w_p1, b_p1, out, p0w, p1w);
        norm_kernel<VD0><<<(N_NODES * 64 + 255) / 256, 256, 0, stream>>>(vis0, inv0);
        norm_kernel<VD1><<<(N_NODES * 64 + 255) / 256, 256, 0, stream>>>(vis1, inv1);
        edge_kernel<VD0><<<(NE * 64 + 255) / 256, 256, 0, stream>>>(vis0, ei0, inv0, p0w, out);
        edge_kernel<VD1><<<(NE * 64 + 255) / 256, 256, 0, stream>>>(vis1, ei1, inv1, p1w, out);
    }
}